// Round 2
// baseline (515.490 us; speedup 1.0000x reference)
//
#include <hip/hip_runtime.h>
#include <math.h>

#define N_NODES 100000
#define N_EDGES 1600000
#define IN_DIM  256
#define HIDDEN  64

// histogram/scatter tiling
#define NB        64      // blocks for edge passes
#define EPB       25000   // edges per block (NB * EPB == N_EDGES exactly)
#define DRANGE    51200   // deg nodes per LDS pass (bytes); 2 passes cover 102400
#define DWORDS    12800   // DRANGE/4 packed u32 words
#define SRANGE    14336   // scatter nodes per LDS pass (floats, 57,344 B)
#define SR        7       // 7*14336 = 100352 >= N_NODES

// ---------------------------------------------------------------------------
// K1: v[i] = sum_j W[i][j]*w2[j];  c = b.w2 + b2   (collapse hidden dim)
// ---------------------------------------------------------------------------
__global__ void wv_kernel(const float* __restrict__ W, const float* __restrict__ b,
                          const float* __restrict__ w2, const float* __restrict__ b2,
                          float* __restrict__ v, float* __restrict__ c) {
    int i = threadIdx.x;  // 256 threads
    float acc = 0.f;
    #pragma unroll 8
    for (int j = 0; j < HIDDEN; ++j) acc += W[i * HIDDEN + j] * w2[j];
    v[i] = acc;
    if (i == 0) {
        float cc = b2[0];
        for (int j = 0; j < HIDDEN; ++j) cc += b[j] * w2[j];
        *c = cc;
    }
}

// ---------------------------------------------------------------------------
// K2: s[n] = x[n] . v  — one wave per node row (64 lanes x float4 = 1 KiB row)
// ---------------------------------------------------------------------------
__global__ void s_kernel(const float* __restrict__ x, const float* __restrict__ v,
                         float* __restrict__ s) {
    const int wave = threadIdx.x >> 6;
    const int lane = threadIdx.x & 63;
    const int n = blockIdx.x * 4 + wave;   // grid = 25000 -> exactly N
    const float4* xr = (const float4*)(x + (size_t)n * IN_DIM);
    const float4* vr = (const float4*)v;
    float4 a  = xr[lane];
    float4 vv = vr[lane];
    float d = a.x * vv.x + a.y * vv.y + a.z * vv.z + a.w * vv.w;
    #pragma unroll
    for (int off = 32; off > 0; off >>= 1) d += __shfl_down(d, off, 64);
    if (lane == 0) s[n] = d;
}

// ---------------------------------------------------------------------------
// K3: per-block private byte-packed degree histogram (NO device atomics).
// Each block owns EPB edges; 2 LDS passes of 51200 nodes (4 nodes per u32).
// Per-block per-node count <= node degree (~45 for this dataset) < 256.
// ---------------------------------------------------------------------------
__global__ void __launch_bounds__(256) deg_hist_kernel(const int* __restrict__ dst,
                                                       unsigned* __restrict__ partialD) {
    __shared__ unsigned hist[DWORDS];
    const int e0 = blockIdx.x * EPB;
    for (int r = 0; r < 2; ++r) {
        const int nbase = r * DRANGE;
        for (int i = threadIdx.x; i < DWORDS; i += 256) hist[i] = 0u;
        __syncthreads();
        for (int k = threadIdx.x; k < EPB; k += 256) {
            int d = dst[e0 + k] - nbase;
            if ((unsigned)d < (unsigned)DRANGE)
                atomicAdd(&hist[d >> 2], 1u << ((d & 3) * 8));
        }
        __syncthreads();
        unsigned* outp = partialD + (size_t)(blockIdx.x * 2 + r) * DWORDS;
        for (int i = threadIdx.x; i < DWORDS; i += 256) outp[i] = hist[i];
        __syncthreads();
    }
}

// ---------------------------------------------------------------------------
// K4: merge byte-packed partials -> deg; fuse dinv = rsqrt(deg+1), t = dinv*s.
// One thread per packed word (4 nodes); words >= 25000 are all-padding.
// ---------------------------------------------------------------------------
__global__ void deg_merge_kernel(const unsigned* __restrict__ partialD,
                                 const float* __restrict__ s,
                                 float* __restrict__ dinv, float* __restrict__ t) {
    int w = blockIdx.x * blockDim.x + threadIdx.x;   // word-column in [0, 2*DWORDS)
    if (w >= N_NODES / 4) return;                    // 25000 full words cover all nodes
    const int r = w / DWORDS, j = w - r * DWORDS;
    unsigned a0 = 0, a1 = 0, a2 = 0, a3 = 0;
    #pragma unroll 8
    for (int b = 0; b < NB; ++b) {
        unsigned p = partialD[(size_t)(b * 2 + r) * DWORDS + j];
        a0 += p & 255u; a1 += (p >> 8) & 255u; a2 += (p >> 16) & 255u; a3 += p >> 24;
    }
    const int n0 = w * 4;
    float4 sv = *(const float4*)(s + n0);
    float4 di, tv;
    di.x = rsqrtf((float)(a0 + 1)); di.y = rsqrtf((float)(a1 + 1));
    di.z = rsqrtf((float)(a2 + 1)); di.w = rsqrtf((float)(a3 + 1));
    tv.x = di.x * sv.x; tv.y = di.y * sv.y; tv.z = di.z * sv.z; tv.w = di.w * sv.w;
    *(float4*)(dinv + n0) = di;
    *(float4*)(t + n0) = tv;
}

// ---------------------------------------------------------------------------
// K5: per-block private float scatter accumulators (NO device atomics).
// 7 LDS passes of 14336 nodes; LDS fire-and-forget ds_add_f32.
// ---------------------------------------------------------------------------
__global__ void __launch_bounds__(256) scat_hist_kernel(const int* __restrict__ src,
                                                        const int* __restrict__ dst,
                                                        const float* __restrict__ t,
                                                        float* __restrict__ partialU) {
    __shared__ float acc[SRANGE];
    const int e0 = blockIdx.x * EPB;
    for (int r = 0; r < SR; ++r) {
        const int nbase = r * SRANGE;
        for (int i = threadIdx.x; i < SRANGE; i += 256) acc[i] = 0.f;
        __syncthreads();
        for (int k = threadIdx.x; k < EPB; k += 256) {
            int e = e0 + k;
            int d = dst[e] - nbase;
            if ((unsigned)d < (unsigned)SRANGE)
                atomicAdd(&acc[d], t[src[e]]);
        }
        __syncthreads();
        float* outp = partialU + (size_t)(blockIdx.x * SR + r) * SRANGE;
        for (int i = threadIdx.x; i < SRANGE; i += 256) outp[i] = acc[i];
        __syncthreads();
    }
}

// ---------------------------------------------------------------------------
// K6: merge scatter partials + sigmoid epilogue.
// out[n] = sigmoid(dinv*(u + dinv*s) + c), u = sum_b partialU[b][n]
// ---------------------------------------------------------------------------
__global__ void merge_final_kernel(const float* __restrict__ partialU,
                                   const float* __restrict__ dinv,
                                   const float* __restrict__ s,
                                   const float* __restrict__ c,
                                   float* __restrict__ out) {
    int n = blockIdx.x * blockDim.x + threadIdx.x;
    if (n >= N_NODES) return;
    const int r = n / SRANGE, j = n - r * SRANGE;
    float u = 0.f;
    #pragma unroll 8
    for (int b = 0; b < NB; ++b)
        u += partialU[(size_t)(b * SR + r) * SRANGE + j];
    float di = dinv[n];
    float pre = di * (u + di * s[n]) + c[0];
    out[n] = 1.f / (1.f + expf(-pre));
}

// ------------------------- fallback path (R1, validated) --------------------
__global__ void deg_kernel(const int* __restrict__ dst, int* __restrict__ cnt) {
    int e = blockIdx.x * blockDim.x + threadIdx.x;
    if (e < N_EDGES) atomicAdd(&cnt[dst[e]], 1);
}
__global__ void dinv_kernel(const int* __restrict__ cnt, const float* __restrict__ s,
                            float* __restrict__ dinv, float* __restrict__ t) {
    int n = blockIdx.x * blockDim.x + threadIdx.x;
    if (n < N_NODES) {
        float di = rsqrtf((float)(cnt[n] + 1));
        dinv[n] = di;
        t[n] = di * s[n];
    }
}
__global__ void scatter_kernel(const int* __restrict__ src, const int* __restrict__ dst,
                               const float* __restrict__ t, float* __restrict__ u) {
    int e = blockIdx.x * blockDim.x + threadIdx.x;
    if (e < N_EDGES) atomicAdd(&u[dst[e]], t[src[e]]);
}
__global__ void final_kernel(const float* __restrict__ dinv, const float* __restrict__ u,
                             const float* __restrict__ s, const float* __restrict__ c,
                             float* __restrict__ out) {
    int n = blockIdx.x * blockDim.x + threadIdx.x;
    if (n < N_NODES) {
        float di = dinv[n];
        float pre = di * (u[n] + di * s[n]) + c[0];
        out[n] = 1.f / (1.f + expf(-pre));
    }
}
// ----------------------------------------------------------------------------

extern "C" void kernel_launch(void* const* d_in, const int* in_sizes, int n_in,
                              void* d_out, int out_size, void* d_ws, size_t ws_size,
                              hipStream_t stream) {
    const float* x   = (const float*)d_in[0];   // [N, 256]
    const int*   ei  = (const int*)  d_in[1];   // [2, E]: src then dst
    const float* W   = (const float*)d_in[2];   // [256, 64]
    const float* b   = (const float*)d_in[3];   // [64]
    const float* w2  = (const float*)d_in[4];   // [64]
    const float* b2  = (const float*)d_in[5];   // [1]
    float* out = (float*)d_out;

    const int* src = ei;
    const int* dst = ei + N_EDGES;

    float* ws   = (float*)d_ws;
    float*    v        = ws + 0;        // 256
    float*    c        = ws + 256;      // 1
    float*    s        = ws + 512;      // 100000
    float*    t        = ws + 100608;   // 100000
    float*    dinv     = ws + 200704;   // 100000
    unsigned* partialD = (unsigned*)(ws + 300800);  // 64*2*12800 = 1,638,400 words
    float*    partialU = ws + 1939200;              // 64*7*14336 = 6,422,528 floats
    const size_t need_bytes = (size_t)(1939200 + NB * SR * SRANGE) * 4;  // ~33.4 MB

    wv_kernel<<<1, 256, 0, stream>>>(W, b, w2, b2, v, c);
    s_kernel<<<N_NODES / 4, 256, 0, stream>>>(x, v, s);

    if (ws_size >= need_bytes) {
        // fast path: LDS-private histograms, no device atomics
        deg_hist_kernel<<<NB, 256, 0, stream>>>(dst, partialD);
        deg_merge_kernel<<<(N_NODES / 4 + 255) / 256, 256, 0, stream>>>(partialD, s, dinv, t);
        scat_hist_kernel<<<NB, 256, 0, stream>>>(src, dst, t, partialU);
        merge_final_kernel<<<(N_NODES + 255) / 256, 256, 0, stream>>>(partialU, dinv, s, c, out);
    } else {
        // fallback: validated device-atomic path (needs zeroed u/cnt)
        float* u   = ws + 300800;
        int*   cnt = (int*)(ws + 400800);
        hipMemsetAsync((char*)d_ws + (size_t)300800 * 4, 0, (size_t)200000 * 4, stream);
        deg_kernel<<<(N_EDGES + 255) / 256, 256, 0, stream>>>(dst, cnt);
        dinv_kernel<<<(N_NODES + 255) / 256, 256, 0, stream>>>(cnt, s, dinv, t);
        scatter_kernel<<<(N_EDGES + 255) / 256, 256, 0, stream>>>(src, dst, t, u);
        final_kernel<<<(N_NODES + 255) / 256, 256, 0, stream>>>(dinv, u, s, c, out);
    }
}

// Round 3
// 213.918 us; speedup vs baseline: 2.4098x; 2.4098x over previous
//
#include <hip/hip_runtime.h>
#include <math.h>

#define N_NODES 100000
#define N_EDGES 1600000
#define IN_DIM  256
#define HIDDEN  64

// ---- scatter tiling: grid = NB edge-chunks x SR node-ranges -----------------
#define NB      64          // edge chunks
#define EPB     25000       // edges per chunk (NB*EPB == N_EDGES)
#define QPB     6250        // int4 groups per chunk
#define SR      8           // node ranges
#define SRANGE  12544       // nodes per range (8*12544 = 100352 >= N); LDS 50,176 B

// ---- degree tiling: grid = NB edge-chunks x PD ranges, byte-packed ----------
#define PD      4           // degree passes
#define DNR     25600       // nodes per degree range (4*25600 = 102400)
#define DW      6400        // packed u32 words per range (DNR/4); LDS 25,600 B

// ---------------------------------------------------------------------------
// K1: v[i] = sum_j W[i][j]*w2[j];  c = b.w2 + b2   (collapse hidden dim)
// ---------------------------------------------------------------------------
__global__ void wv_kernel(const float* __restrict__ W, const float* __restrict__ b,
                          const float* __restrict__ w2, const float* __restrict__ b2,
                          float* __restrict__ v, float* __restrict__ c) {
    int i = threadIdx.x;  // 256 threads
    float acc = 0.f;
    #pragma unroll 8
    for (int j = 0; j < HIDDEN; ++j) acc += W[i * HIDDEN + j] * w2[j];
    v[i] = acc;
    if (i == 0) {
        float cc = b2[0];
        for (int j = 0; j < HIDDEN; ++j) cc += b[j] * w2[j];
        *c = cc;
    }
}

// ---------------------------------------------------------------------------
// K2: s[n] = x[n] . v  — one wave per node row (64 lanes x float4 = 1 KiB row)
// ---------------------------------------------------------------------------
__global__ void s_kernel(const float* __restrict__ x, const float* __restrict__ v,
                         float* __restrict__ s) {
    const int wave = threadIdx.x >> 6;
    const int lane = threadIdx.x & 63;
    const int n = blockIdx.x * 4 + wave;   // grid = 25000 -> exactly N
    const float4* xr = (const float4*)(x + (size_t)n * IN_DIM);
    const float4* vr = (const float4*)v;
    float4 a  = xr[lane];
    float4 vv = vr[lane];
    float d = a.x * vv.x + a.y * vv.y + a.z * vv.z + a.w * vv.w;
    #pragma unroll
    for (int off = 32; off > 0; off >>= 1) d += __shfl_down(d, off, 64);
    if (lane == 0) s[n] = d;
}

// ---------------------------------------------------------------------------
// K3: degree histogram, byte-packed, 2D grid (chunk x range). int4 dst loads.
// blockIdx.x = chunk*PD + range. Per-block per-node count << 256 (1/64 of
// edges per chunk; Poisson(16) overall) — no byte overflow.
// ---------------------------------------------------------------------------
__global__ void __launch_bounds__(512) deg_hist_kernel(const int4* __restrict__ dst4,
                                                       unsigned* __restrict__ partialD) {
    __shared__ unsigned hist[DW];
    const int r  = blockIdx.x & (PD - 1);
    const int bb = blockIdx.x >> 2;            // PD == 4
    const int nbase = r * DNR;
    for (int i = threadIdx.x; i < DW; i += 512) hist[i] = 0u;
    __syncthreads();
    const int q0 = bb * QPB;
    for (int k = threadIdx.x; k < QPB; k += 512) {
        int4 d4 = dst4[q0 + k];
        int d0 = d4.x - nbase, d1 = d4.y - nbase, d2 = d4.z - nbase, d3 = d4.w - nbase;
        if ((unsigned)d0 < (unsigned)DNR) atomicAdd(&hist[d0 >> 2], 1u << ((d0 & 3) * 8));
        if ((unsigned)d1 < (unsigned)DNR) atomicAdd(&hist[d1 >> 2], 1u << ((d1 & 3) * 8));
        if ((unsigned)d2 < (unsigned)DNR) atomicAdd(&hist[d2 >> 2], 1u << ((d2 & 3) * 8));
        if ((unsigned)d3 < (unsigned)DNR) atomicAdd(&hist[d3 >> 2], 1u << ((d3 & 3) * 8));
    }
    __syncthreads();
    unsigned* outp = partialD + (size_t)blockIdx.x * DW;  // (bb*PD + r) * DW
    for (int i = threadIdx.x; i < DW; i += 512) outp[i] = hist[i];
}

// ---------------------------------------------------------------------------
// K4: merge byte-packed partials -> deg; fuse dinv = rsqrt(deg+1), t = dinv*s.
// One thread per packed word (4 nodes). Coalesced over j.
// ---------------------------------------------------------------------------
__global__ void deg_merge_kernel(const unsigned* __restrict__ partialD,
                                 const float* __restrict__ s,
                                 float* __restrict__ dinv, float* __restrict__ t) {
    int w = blockIdx.x * blockDim.x + threadIdx.x;   // global word id
    if (w >= N_NODES / 4) return;                    // 25000 words cover all nodes
    const int r = w / DW, j = w - r * DW;
    unsigned a0 = 0, a1 = 0, a2 = 0, a3 = 0;
    #pragma unroll 8
    for (int b = 0; b < NB; ++b) {
        unsigned p = partialD[(size_t)(b * PD + r) * DW + j];
        a0 += p & 255u; a1 += (p >> 8) & 255u; a2 += (p >> 16) & 255u; a3 += p >> 24;
    }
    const int n0 = w * 4;
    float4 sv = *(const float4*)(s + n0);
    float4 di, tv;
    di.x = rsqrtf((float)(a0 + 1)); di.y = rsqrtf((float)(a1 + 1));
    di.z = rsqrtf((float)(a2 + 1)); di.w = rsqrtf((float)(a3 + 1));
    tv.x = di.x * sv.x; tv.y = di.y * sv.y; tv.z = di.z * sv.z; tv.w = di.w * sv.w;
    *(float4*)(dinv + n0) = di;
    *(float4*)(t + n0) = tv;
}

// ---------------------------------------------------------------------------
// K5: scatter u[dst] += t[src] via LDS-private accumulators, 2D grid
// (chunk x range). int4 dst/src loads -> 4 independent conditional gathers.
// ---------------------------------------------------------------------------
__global__ void __launch_bounds__(512) scat_hist_kernel(const int4* __restrict__ src4,
                                                        const int4* __restrict__ dst4,
                                                        const float* __restrict__ t,
                                                        float* __restrict__ partialU) {
    __shared__ float acc[SRANGE];
    const int r  = blockIdx.x & (SR - 1);
    const int bb = blockIdx.x >> 3;            // SR == 8
    const int nbase = r * SRANGE;
    for (int i = threadIdx.x; i < SRANGE; i += 512) acc[i] = 0.f;
    __syncthreads();
    const int q0 = bb * QPB;
    for (int k = threadIdx.x; k < QPB; k += 512) {
        int4 d4 = dst4[q0 + k];
        int4 s4 = src4[q0 + k];
        int d0 = d4.x - nbase, d1 = d4.y - nbase, d2 = d4.z - nbase, d3 = d4.w - nbase;
        if ((unsigned)d0 < (unsigned)SRANGE) atomicAdd(&acc[d0], t[s4.x]);
        if ((unsigned)d1 < (unsigned)SRANGE) atomicAdd(&acc[d1], t[s4.y]);
        if ((unsigned)d2 < (unsigned)SRANGE) atomicAdd(&acc[d2], t[s4.z]);
        if ((unsigned)d3 < (unsigned)SRANGE) atomicAdd(&acc[d3], t[s4.w]);
    }
    __syncthreads();
    float* outp = partialU + (size_t)blockIdx.x * SRANGE;  // (bb*SR + r) * SRANGE
    for (int i = threadIdx.x; i < SRANGE; i += 512) outp[i] = acc[i];
}

// ---------------------------------------------------------------------------
// K6: merge scatter partials + sigmoid epilogue.
// ---------------------------------------------------------------------------
__global__ void merge_final_kernel(const float* __restrict__ partialU,
                                   const float* __restrict__ dinv,
                                   const float* __restrict__ s,
                                   const float* __restrict__ c,
                                   float* __restrict__ out) {
    int n = blockIdx.x * blockDim.x + threadIdx.x;
    if (n >= N_NODES) return;
    const int r = n / SRANGE, j = n - r * SRANGE;
    float u = 0.f;
    #pragma unroll 8
    for (int b = 0; b < NB; ++b)
        u += partialU[(size_t)(b * SR + r) * SRANGE + j];
    float di = dinv[n];
    float pre = di * (u + di * s[n]) + c[0];
    out[n] = 1.f / (1.f + expf(-pre));
}

// ------------------------- fallback path (R1, validated) --------------------
__global__ void deg_kernel(const int* __restrict__ dst, int* __restrict__ cnt) {
    int e = blockIdx.x * blockDim.x + threadIdx.x;
    if (e < N_EDGES) atomicAdd(&cnt[dst[e]], 1);
}
__global__ void dinv_kernel(const int* __restrict__ cnt, const float* __restrict__ s,
                            float* __restrict__ dinv, float* __restrict__ t) {
    int n = blockIdx.x * blockDim.x + threadIdx.x;
    if (n < N_NODES) {
        float di = rsqrtf((float)(cnt[n] + 1));
        dinv[n] = di;
        t[n] = di * s[n];
    }
}
__global__ void scatter_kernel(const int* __restrict__ src, const int* __restrict__ dst,
                               const float* __restrict__ t, float* __restrict__ u) {
    int e = blockIdx.x * blockDim.x + threadIdx.x;
    if (e < N_EDGES) atomicAdd(&u[dst[e]], t[src[e]]);
}
__global__ void final_kernel(const float* __restrict__ dinv, const float* __restrict__ u,
                             const float* __restrict__ s, const float* __restrict__ c,
                             float* __restrict__ out) {
    int n = blockIdx.x * blockDim.x + threadIdx.x;
    if (n < N_NODES) {
        float di = dinv[n];
        float pre = di * (u[n] + di * s[n]) + c[0];
        out[n] = 1.f / (1.f + expf(-pre));
    }
}
// ----------------------------------------------------------------------------

extern "C" void kernel_launch(void* const* d_in, const int* in_sizes, int n_in,
                              void* d_out, int out_size, void* d_ws, size_t ws_size,
                              hipStream_t stream) {
    const float* x   = (const float*)d_in[0];   // [N, 256]
    const int*   ei  = (const int*)  d_in[1];   // [2, E]: src then dst
    const float* W   = (const float*)d_in[2];   // [256, 64]
    const float* b   = (const float*)d_in[3];   // [64]
    const float* w2  = (const float*)d_in[4];   // [64]
    const float* b2  = (const float*)d_in[5];   // [1]
    float* out = (float*)d_out;

    const int* src = ei;
    const int* dst = ei + N_EDGES;

    float* ws   = (float*)d_ws;
    float*    v        = ws + 0;        // 256
    float*    c        = ws + 256;      // 1
    float*    s        = ws + 512;      // 100000
    float*    t        = ws + 100608;   // 100000
    float*    dinv     = ws + 200704;   // 100000
    unsigned* partialD = (unsigned*)(ws + 300800);  // 64*4*6400 = 1,638,400 words
    float*    partialU = ws + 1939200;              // 64*8*12544 = 6,422,528 floats
    const size_t need_bytes = (size_t)(1939200 + NB * SR * SRANGE) * 4;  // 33.45 MB (== R2 validated)

    wv_kernel<<<1, 256, 0, stream>>>(W, b, w2, b2, v, c);
    s_kernel<<<N_NODES / 4, 256, 0, stream>>>(x, v, s);

    if (ws_size >= need_bytes) {
        deg_hist_kernel<<<NB * PD, 512, 0, stream>>>((const int4*)dst, partialD);
        deg_merge_kernel<<<(N_NODES / 4 + 255) / 256, 256, 0, stream>>>(partialD, s, dinv, t);
        scat_hist_kernel<<<NB * SR, 512, 0, stream>>>((const int4*)src, (const int4*)dst, t, partialU);
        merge_final_kernel<<<(N_NODES + 255) / 256, 256, 0, stream>>>(partialU, dinv, s, c, out);
    } else {
        // fallback: validated device-atomic path (needs zeroed u/cnt)
        float* u   = ws + 300800;
        int*   cnt = (int*)(ws + 400800);
        hipMemsetAsync((char*)d_ws + (size_t)300800 * 4, 0, (size_t)200000 * 4, stream);
        deg_kernel<<<(N_EDGES + 255) / 256, 256, 0, stream>>>(dst, cnt);
        dinv_kernel<<<(N_NODES + 255) / 256, 256, 0, stream>>>(cnt, s, dinv, t);
        scatter_kernel<<<(N_EDGES + 255) / 256, 256, 0, stream>>>(src, dst, t, u);
        final_kernel<<<(N_NODES + 255) / 256, 256, 0, stream>>>(dinv, u, s, c, out);
    }
}